// Round 1
// baseline (1597.335 us; speedup 1.0000x reference)
//
#include <hip/hip_runtime.h>
#include <hip/hip_bf16.h>
#include <math.h>

#define NTOK 8192      // B*T = 4*2048
#define DDIM 1024
#define HDIM 4096
#define NEXP 8
#define HROWS (NTOK*2 + 128)   // compact pair rows + pad for last-tile overread

typedef unsigned int u32;
typedef unsigned short u16;
typedef __bf16 bf16x8 __attribute__((ext_vector_type(8)));
typedef float f32x4 __attribute__((ext_vector_type(4)));
typedef u16 u16x8 __attribute__((ext_vector_type(8)));
typedef u16 u16x4 __attribute__((ext_vector_type(4)));

__device__ __forceinline__ u16 f2bf(float f){
  u32 u = __builtin_bit_cast(u32, f);
  u32 r = (u + 0x7FFFu + ((u >> 16) & 1u)) >> 16;   // RNE
  return (u16)r;
}
__device__ __forceinline__ float bf2f(u16 b){
  u32 u = ((u32)b) << 16;
  return __builtin_bit_cast(float, u);
}
__device__ __forceinline__ void gl_lds16(const void* g, void* l){
  __builtin_amdgcn_global_load_lds(
      (const __attribute__((address_space(1))) u32*)g,
      (__attribute__((address_space(3))) u32*)l, 16, 0, 0);
}

// ---------------- convert x fp32 -> bf16 ----------------
__global__ __launch_bounds__(256) void cvtx_kernel(const float* __restrict__ x,
                                                   u16* __restrict__ xb){
  long i = (long)(blockIdx.x * 256 + threadIdx.x) * 8;
  float4 a = *(const float4*)(x + i);
  float4 b = *(const float4*)(x + i + 4);
  u16x8 o;
  o[0]=f2bf(a.x); o[1]=f2bf(a.y); o[2]=f2bf(a.z); o[3]=f2bf(a.w);
  o[4]=f2bf(b.x); o[5]=f2bf(b.y); o[6]=f2bf(b.z); o[7]=f2bf(b.w);
  *(u16x8*)(xb + i) = o;
}

// ------------- transpose+convert: in [R][C] fp32 -> out [C][R] bf16, per expert -------------
__global__ __launch_bounds__(256) void transpose_cvt(const float* __restrict__ in,
                                                     u16* __restrict__ out,
                                                     int R, int C){
  int e = blockIdx.z;
  const float* pin = in + (long)e * R * C;
  u16* pout = out + (long)e * R * C;
  __shared__ u16 tile[64][65];
  int c0 = blockIdx.x * 64, r0 = blockIdx.y * 64;
  int tid = threadIdx.x;
#pragma unroll
  for (int j = 0; j < 16; j++){
    int idx = tid + 256 * j;
    int r = idx >> 6, c = idx & 63;
    tile[r][c] = f2bf(pin[(long)(r0 + r) * C + c0 + c]);
  }
  __syncthreads();
#pragma unroll
  for (int j = 0; j < 16; j++){
    int idx = tid + 256 * j;
    int r = idx >> 6, c = idx & 63;       // r: out row local (C-dim), c: out col local (R-dim)
    pout[(long)(c0 + r) * R + r0 + c] = tile[c][r];
  }
}

// ---------------- routing: 1 wave per token ----------------
__global__ __launch_bounds__(256) void route_kernel(const float* __restrict__ x,
                                                    const float* __restrict__ Wr,
                                                    int* __restrict__ elist,
                                                    int4* __restrict__ meta,
                                                    float2* __restrict__ gates,
                                                    int* __restrict__ cnt,
                                                    float* __restrict__ imp){
  int t = (blockIdx.x * 256 + threadIdx.x) >> 6;
  int lane = threadIdx.x & 63;
  const float* xr = x + (long)t * DDIM;
  float acc[NEXP] = {};
  for (int d = lane; d < DDIM; d += 64){
    float xv = xr[d];
    const float* w = Wr + d * NEXP;
#pragma unroll
    for (int e = 0; e < NEXP; e++) acc[e] += xv * w[e];
  }
#pragma unroll
  for (int e = 0; e < NEXP; e++){
#pragma unroll
    for (int off = 32; off; off >>= 1) acc[e] += __shfl_xor(acc[e], off, 64);
  }
  if (lane == 0){
    float mx = acc[0];
#pragma unroll
    for (int e = 1; e < NEXP; e++) mx = fmaxf(mx, acc[e]);
    float p[NEXP]; float s = 0.f;
#pragma unroll
    for (int e = 0; e < NEXP; e++){ p[e] = expf(acc[e] - mx); s += p[e]; }
    float inv = 1.f / s;
#pragma unroll
    for (int e = 0; e < NEXP; e++) p[e] *= inv;
    int i0 = 0; float v0 = p[0];
#pragma unroll
    for (int e = 1; e < NEXP; e++) if (p[e] > v0){ v0 = p[e]; i0 = e; }
    int i1 = -1; float v1 = -1.f;
#pragma unroll
    for (int e = 0; e < NEXP; e++) if (e != i0 && p[e] > v1){ v1 = p[e]; i1 = e; }
    float gs = v0 + v1 + 1e-9f;
    int s0 = atomicAdd(&cnt[i0], 1);
    int s1 = atomicAdd(&cnt[i1], 1);
    elist[i0 * NTOK + s0] = t;
    elist[i1 * NTOK + s1] = t;
    meta[t] = make_int4(i0, i1, s0, s1);
    gates[t] = make_float2(v0 / gs, v1 / gs);
#pragma unroll
    for (int e = 0; e < NEXP; e++) atomicAdd(&imp[e], p[e]);
  }
}

__global__ void offs_kernel(const int* __restrict__ cnt, int* __restrict__ offs){
  if (threadIdx.x == 0 && blockIdx.x == 0){
    int o = 0;
    for (int e = 0; e < NEXP; e++){ offs[e] = o; o += cnt[e]; }
  }
}

// ---------------- GEMM1: h = gelu(X_gathered @ W1[e]) ----------------
// A: gathered token rows of xb [128 x K], B^T: w1t[e] (H,D) rows, tile 128x128, BK=64
__global__ __launch_bounds__(256) void gemm1_kernel(const u16* __restrict__ xb,
                                                    const u16* __restrict__ w1t,
                                                    u16* __restrict__ h,
                                                    const int* __restrict__ elist,
                                                    const int* __restrict__ cnt,
                                                    const int* __restrict__ offs){
  const int e = blockIdx.z;
  const int n_e = cnt[e];
  const int tt = blockIdx.y;
  if (tt * 128 >= n_e) return;
  const int hb = blockIdx.x * 128;
  __shared__ __align__(16) u16 As[128 * 64];
  __shared__ __align__(16) u16 Bs[128 * 64];
  const int tid = threadIdx.x;
  const int colb = (tid & 7) * 8;
  long agb[4]; int arow[4];
#pragma unroll
  for (int q = 0; q < 4; q++){
    int row = q * 32 + (tid >> 3);
    int slot = tt * 128 + row;
    int sl = slot < n_e ? slot : n_e - 1;
    int tok = elist[e * NTOK + sl];
    arow[q] = row;
    agb[q] = (long)tok * DDIM + colb;
  }
  const long bgb = ((long)e * HDIM + hb) * DDIM;
  const int wid = tid >> 6, lane = tid & 63;
  const int wr = (wid >> 1) * 64, wc = (wid & 1) * 64;
  const int fr = lane & 15, fq = lane >> 4;
  f32x4 acc[4][4] = {};
  for (int kb = 0; kb < DDIM; kb += 64){
    __syncthreads();
#pragma unroll
    for (int q = 0; q < 4; q++){
      int row = q * 32 + (tid >> 3);
      gl_lds16(xb + agb[q] + kb, &As[arow[q] * 64 + colb]);
      gl_lds16(w1t + bgb + (long)row * DDIM + kb + colb, &Bs[row * 64 + colb]);
    }
    __syncthreads();
#pragma unroll
    for (int kk = 0; kk < 2; kk++){
      bf16x8 af[4], bfr[4];
#pragma unroll
      for (int m = 0; m < 4; m++) af[m] = *(const bf16x8*)&As[(wr + m * 16 + fr) * 64 + kk * 32 + fq * 8];
#pragma unroll
      for (int n = 0; n < 4; n++) bfr[n] = *(const bf16x8*)&Bs[(wc + n * 16 + fr) * 64 + kk * 32 + fq * 8];
#pragma unroll
      for (int m = 0; m < 4; m++)
#pragma unroll
        for (int n = 0; n < 4; n++)
          acc[m][n] = __builtin_amdgcn_mfma_f32_16x16x32_bf16(af[m], bfr[n], acc[m][n], 0, 0, 0);
    }
  }
  const int hrow0 = offs[e] + tt * 128;
#pragma unroll
  for (int m = 0; m < 4; m++){
#pragma unroll
    for (int j = 0; j < 4; j++){
      int row = wr + m * 16 + fq * 4 + j;
      int slot = tt * 128 + row;
      if (slot >= n_e) continue;
      long base = (long)(hrow0 + row) * HDIM + hb + wc;
#pragma unroll
      for (int n = 0; n < 4; n++){
        float v = acc[m][n][j];
        v = 0.5f * v * (1.0f + erff(v * 0.70710678118f));   // exact gelu
        h[base + n * 16 + fr] = f2bf(v);
      }
    }
  }
}

// ---------------- GEMM2: ypair = h @ W2[e] ----------------
__global__ __launch_bounds__(256) void gemm2_kernel(const u16* __restrict__ h,
                                                    const u16* __restrict__ w2t,
                                                    u16* __restrict__ ypair,
                                                    const int* __restrict__ cnt,
                                                    const int* __restrict__ offs){
  const int e = blockIdx.z;
  const int n_e = cnt[e];
  const int tt = blockIdx.y;
  if (tt * 128 >= n_e) return;
  const int db = blockIdx.x * 128;
  __shared__ __align__(16) u16 As[128 * 64];
  __shared__ __align__(16) u16 Bs[128 * 64];
  const int tid = threadIdx.x;
  const int colb = (tid & 7) * 8;
  const long arow0 = (long)(offs[e] + tt * 128);
  const long bgb = ((long)e * DDIM + db) * HDIM;
  const int wid = tid >> 6, lane = tid & 63;
  const int wr = (wid >> 1) * 64, wc = (wid & 1) * 64;
  const int fr = lane & 15, fq = lane >> 4;
  f32x4 acc[4][4] = {};
  for (int kb = 0; kb < HDIM; kb += 64){
    __syncthreads();
#pragma unroll
    for (int q = 0; q < 4; q++){
      int row = q * 32 + (tid >> 3);
      gl_lds16(h + (arow0 + row) * HDIM + kb + colb, &As[row * 64 + colb]);
      gl_lds16(w2t + bgb + (long)row * HDIM + kb + colb, &Bs[row * 64 + colb]);
    }
    __syncthreads();
#pragma unroll
    for (int kk = 0; kk < 2; kk++){
      bf16x8 af[4], bfr[4];
#pragma unroll
      for (int m = 0; m < 4; m++) af[m] = *(const bf16x8*)&As[(wr + m * 16 + fr) * 64 + kk * 32 + fq * 8];
#pragma unroll
      for (int n = 0; n < 4; n++) bfr[n] = *(const bf16x8*)&Bs[(wc + n * 16 + fr) * 64 + kk * 32 + fq * 8];
#pragma unroll
      for (int m = 0; m < 4; m++)
#pragma unroll
        for (int n = 0; n < 4; n++)
          acc[m][n] = __builtin_amdgcn_mfma_f32_16x16x32_bf16(af[m], bfr[n], acc[m][n], 0, 0, 0);
    }
  }
  const long prow0 = arow0;
#pragma unroll
  for (int m = 0; m < 4; m++){
#pragma unroll
    for (int j = 0; j < 4; j++){
      int row = wr + m * 16 + fq * 4 + j;
      int slot = tt * 128 + row;
      if (slot >= n_e) continue;
      long base = (prow0 + row) * DDIM + db + wc;
#pragma unroll
      for (int n = 0; n < 4; n++) ypair[base + n * 16 + fr] = f2bf(acc[m][n][j]);
    }
  }
}

// ---------------- combine: out[t] = g0*y0 + g1*y1 ----------------
__global__ __launch_bounds__(256) void combine_kernel(const u16* __restrict__ ypair,
                                                      const int4* __restrict__ meta,
                                                      const float2* __restrict__ gates,
                                                      const int* __restrict__ offs,
                                                      float* __restrict__ out){
  int t = blockIdx.x;
  int c = threadIdx.x;
  int4 m = meta[t];
  float2 g = gates[t];
  long p0 = (long)(offs[m.x] + m.z) * DDIM + c * 4;
  long p1 = (long)(offs[m.y] + m.w) * DDIM + c * 4;
  u16x4 y0 = *(const u16x4*)&ypair[p0];
  u16x4 y1 = *(const u16x4*)&ypair[p1];
  float4 o;
  o.x = g.x * bf2f(y0[0]) + g.y * bf2f(y1[0]);
  o.y = g.x * bf2f(y0[1]) + g.y * bf2f(y1[1]);
  o.z = g.x * bf2f(y0[2]) + g.y * bf2f(y1[2]);
  o.w = g.x * bf2f(y0[3]) + g.y * bf2f(y1[3]);
  *(float4*)&out[(long)t * DDIM + c * 4] = o;
}

// ---------------- load-balance loss ----------------
__global__ void lb_kernel(const float* __restrict__ imp, const int* __restrict__ cnt,
                          float* __restrict__ outp){
  if (threadIdx.x == 0 && blockIdx.x == 0){
    float si = 0.f, sl = 0.f;
    for (int e = 0; e < NEXP; e++){ si += imp[e]; sl += (float)cnt[e]; }
    float lb = 0.f;
    for (int e = 0; e < NEXP; e++)
      lb += (imp[e] / (si + 1e-9f)) * ((float)cnt[e] / (sl + 1e-9f));
    outp[0] = lb * (float)NEXP;
  }
}

extern "C" void kernel_launch(void* const* d_in, const int* in_sizes, int n_in,
                              void* d_out, int out_size, void* d_ws, size_t ws_size,
                              hipStream_t stream){
  const float* x  = (const float*)d_in[0];
  const float* Wr = (const float*)d_in[1];
  const float* W1 = (const float*)d_in[2];
  const float* W2 = (const float*)d_in[3];
  float* out = (float*)d_out;
  char* ws = (char*)d_ws;
  size_t off = 0;
  u16* xb = (u16*)(ws + off);   off += (size_t)NTOK * DDIM * 2;
  u16* wt = (u16*)(ws + off);   off += (size_t)NEXP * DDIM * HDIM * 2;   // reused: W1^T then W2^T
  u16* h  = (u16*)(ws + off);   off += (size_t)HROWS * HDIM * 2;
  u16* yp = (u16*)(ws + off);   off += (size_t)NTOK * 2 * DDIM * 2;
  int* elist   = (int*)(ws + off);    off += (size_t)NEXP * NTOK * 4;
  int4* meta   = (int4*)(ws + off);   off += (size_t)NTOK * 16;
  float2* gts  = (float2*)(ws + off); off += (size_t)NTOK * 8;
  int* cnt     = (int*)(ws + off);    off += 32;
  float* imp   = (float*)(ws + off);  off += 32;
  int* offs    = (int*)(ws + off);    off += 32;
  if (ws_size < off) return;  // insufficient workspace: fail visibly

  hipMemsetAsync(cnt, 0, 64, stream);   // cnt[8] + imp[8]
  cvtx_kernel<<<4096, 256, 0, stream>>>(x, xb);
  route_kernel<<<NTOK / 4, 256, 0, stream>>>(x, Wr, elist, meta, gts, cnt, imp);
  offs_kernel<<<1, 64, 0, stream>>>(cnt, offs);
  transpose_cvt<<<dim3(HDIM / 64, DDIM / 64, NEXP), 256, 0, stream>>>(W1, wt, DDIM, HDIM);
  gemm1_kernel<<<dim3(HDIM / 128, NTOK / 128, NEXP), 256, 0, stream>>>(xb, wt, h, elist, cnt, offs);
  transpose_cvt<<<dim3(DDIM / 64, HDIM / 64, NEXP), 256, 0, stream>>>(W2, wt, HDIM, DDIM);
  gemm2_kernel<<<dim3(DDIM / 128, NTOK / 128, NEXP), 256, 0, stream>>>(h, wt, yp, cnt, offs);
  combine_kernel<<<NTOK, 256, 0, stream>>>(yp, meta, gts, offs, out);
  lb_kernel<<<1, 64, 0, stream>>>(imp, cnt, out + (size_t)NTOK * DDIM);
}

// Round 2
// 598.725 us; speedup vs baseline: 2.6679x; 2.6679x over previous
//
#include <hip/hip_runtime.h>
#include <hip/hip_bf16.h>
#include <math.h>

#define NTOK 8192      // B*T = 4*2048
#define DDIM 1024
#define HDIM 4096
#define NEXP 8
#define HROWS (NTOK*2 + 128)   // compact pair rows + pad for last-tile overread
#define RBLK 512               // route blocks (16 tokens each)

typedef unsigned int u32;
typedef unsigned short u16;
typedef __bf16 bf16x8 __attribute__((ext_vector_type(8)));
typedef float f32x4 __attribute__((ext_vector_type(4)));
typedef u16 u16x8 __attribute__((ext_vector_type(8)));
typedef u16 u16x4 __attribute__((ext_vector_type(4)));

__device__ __forceinline__ u16 f2bf(float f){
  u32 u = __builtin_bit_cast(u32, f);
  u32 r = (u + 0x7FFFu + ((u >> 16) & 1u)) >> 16;   // RNE
  return (u16)r;
}
__device__ __forceinline__ float bf2f(u16 b){
  u32 u = ((u32)b) << 16;
  return __builtin_bit_cast(float, u);
}
__device__ __forceinline__ void gl_lds16(const void* g, void* l){
  __builtin_amdgcn_global_load_lds(
      (const __attribute__((address_space(1))) u32*)g,
      (__attribute__((address_space(3))) u32*)l, 16, 0, 0);
}

// ---------------- convert x fp32 -> bf16 ----------------
__global__ __launch_bounds__(256) void cvtx_kernel(const float* __restrict__ x,
                                                   u16* __restrict__ xb){
  long i = (long)(blockIdx.x * 256 + threadIdx.x) * 8;
  float4 a = *(const float4*)(x + i);
  float4 b = *(const float4*)(x + i + 4);
  u16x8 o;
  o[0]=f2bf(a.x); o[1]=f2bf(a.y); o[2]=f2bf(a.z); o[3]=f2bf(a.w);
  o[4]=f2bf(b.x); o[5]=f2bf(b.y); o[6]=f2bf(b.z); o[7]=f2bf(b.w);
  *(u16x8*)(xb + i) = o;
}

// ------------- transpose+convert: in [R][C] fp32 -> out [C][R] bf16, per expert -------------
__global__ __launch_bounds__(256) void transpose_cvt(const float* __restrict__ in,
                                                     u16* __restrict__ out,
                                                     int R, int C){
  int e = blockIdx.z;
  const float* pin = in + (long)e * R * C;
  u16* pout = out + (long)e * R * C;
  __shared__ u16 tile[64][65];
  int c0 = blockIdx.x * 64, r0 = blockIdx.y * 64;
  int tid = threadIdx.x;
#pragma unroll
  for (int j = 0; j < 16; j++){
    int idx = tid + 256 * j;
    int r = idx >> 6, c = idx & 63;
    tile[r][c] = f2bf(pin[(long)(r0 + r) * C + c0 + c]);
  }
  __syncthreads();
#pragma unroll
  for (int j = 0; j < 16; j++){
    int idx = tid + 256 * j;
    int r = idx >> 6, c = idx & 63;
    pout[(long)(c0 + r) * R + r0 + c] = tile[c][r];
  }
}

// ---------------- routing phase 1: 1 wave per token, no global atomics ----------------
// Writes: meta(i0,i1), gates, selrk[m]=(rank<<3)|e per assignment m=t*2+c,
//         blockhist[b*8+e], impPart[b*8+e]
__global__ __launch_bounds__(1024) void route_kernel(const float* __restrict__ x,
                                                     const float* __restrict__ Wr,
                                                     int4* __restrict__ meta,
                                                     float2* __restrict__ gates,
                                                     int* __restrict__ selrk,
                                                     int* __restrict__ blockhist,
                                                     float* __restrict__ impPart){
  const int wid = threadIdx.x >> 6;       // 0..15 (token within block)
  const int lane = threadIdx.x & 63;
  const int t = blockIdx.x * 16 + wid;
  const float* xr = x + (long)t * DDIM;
  float acc[NEXP] = {};
  for (int d0 = lane * 4; d0 < DDIM; d0 += 256){
    float4 xv = *(const float4*)(xr + d0);
    const float* w = Wr + d0 * NEXP;
#pragma unroll
    for (int q = 0; q < 4; q++){
      float xq = ((const float*)&xv)[q];
      float4 w0 = *(const float4*)(w + q * NEXP);
      float4 w1 = *(const float4*)(w + q * NEXP + 4);
      acc[0] += xq * w0.x; acc[1] += xq * w0.y; acc[2] += xq * w0.z; acc[3] += xq * w0.w;
      acc[4] += xq * w1.x; acc[5] += xq * w1.y; acc[6] += xq * w1.z; acc[7] += xq * w1.w;
    }
  }
#pragma unroll
  for (int e = 0; e < NEXP; e++){
#pragma unroll
    for (int off = 32; off; off >>= 1) acc[e] += __shfl_xor(acc[e], off, 64);
  }
  __shared__ int sel_s[32];
  __shared__ float p_s[16][NEXP];
  if (lane == 0){
    float mx = acc[0];
#pragma unroll
    for (int e = 1; e < NEXP; e++) mx = fmaxf(mx, acc[e]);
    float p[NEXP]; float s = 0.f;
#pragma unroll
    for (int e = 0; e < NEXP; e++){ p[e] = expf(acc[e] - mx); s += p[e]; }
    float inv = 1.f / s;
#pragma unroll
    for (int e = 0; e < NEXP; e++){ p[e] *= inv; p_s[wid][e] = p[e]; }
    int i0 = 0; float v0 = p[0];
#pragma unroll
    for (int e = 1; e < NEXP; e++) if (p[e] > v0){ v0 = p[e]; i0 = e; }
    int i1 = -1; float v1 = -1.f;
#pragma unroll
    for (int e = 0; e < NEXP; e++) if (e != i0 && p[e] > v1){ v1 = p[e]; i1 = e; }
    float gs = v0 + v1 + 1e-9f;
    meta[t] = make_int4(i0, i1, 0, 0);
    gates[t] = make_float2(v0 / gs, v1 / gs);
    sel_s[wid * 2] = i0;
    sel_s[wid * 2 + 1] = i1;
  }
  __syncthreads();
  const int tid = threadIdx.x;
  if (tid < 32){
    int e = sel_s[tid];
    int r = 0;
    for (int m = 0; m < tid; m++) r += (sel_s[m] == e) ? 1 : 0;
    selrk[blockIdx.x * 32 + tid] = (r << 3) | e;
  }
  if (tid < NEXP){
    int hcount = 0;
#pragma unroll
    for (int m = 0; m < 32; m++) hcount += (sel_s[m] == tid) ? 1 : 0;
    blockhist[blockIdx.x * NEXP + tid] = hcount;
    float s = 0.f;
#pragma unroll
    for (int w = 0; w < 16; w++) s += p_s[w][tid];
    impPart[blockIdx.x * NEXP + tid] = s;
  }
}

// ---------------- routing phase 2: exclusive scan of block histograms ----------------
__global__ __launch_bounds__(512) void scan_kernel(int* __restrict__ blockhist,
                                                   const float* __restrict__ impPart,
                                                   int* __restrict__ cnt,
                                                   int* __restrict__ offs,
                                                   float* __restrict__ imp){
  const int e = threadIdx.x >> 6;     // expert 0..7
  const int lane = threadIdx.x & 63;
  const int base = lane * 8;          // 8 blocks per lane, 512 total
  int v[8]; int s = 0;
#pragma unroll
  for (int i = 0; i < 8; i++){
    int tmp = blockhist[(base + i) * NEXP + e];
    v[i] = s; s += tmp;
  }
  int inc = s;
#pragma unroll
  for (int off = 1; off < 64; off <<= 1){
    int o = __shfl_up(inc, off, 64);
    if (lane >= off) inc += o;
  }
  int excl = inc - s;
#pragma unroll
  for (int i = 0; i < 8; i++) blockhist[(base + i) * NEXP + e] = v[i] + excl;
  int tot = __shfl(inc, 63, 64);
  float fs = 0.f;
#pragma unroll
  for (int i = 0; i < 8; i++) fs += impPart[(base + i) * NEXP + e];
#pragma unroll
  for (int off = 32; off; off >>= 1) fs += __shfl_xor(fs, off, 64);
  __shared__ int cnt_s[NEXP];
  if (lane == 0){ cnt_s[e] = tot; cnt[e] = tot; imp[e] = fs; }
  __syncthreads();
  if (threadIdx.x == 0){
    int o = 0;
    for (int q = 0; q < NEXP; q++){ offs[q] = o; o += cnt_s[q]; }
  }
}

// ---------------- routing phase 3: write compact expert lists + slots ----------------
__global__ __launch_bounds__(256) void fill_kernel(const int* __restrict__ selrk,
                                                   const int* __restrict__ blockhist,
                                                   int* __restrict__ elist,
                                                   int4* __restrict__ meta){
  int m = blockIdx.x * 256 + threadIdx.x;   // assignment index, 0..2*NTOK-1
  int t = m >> 1, c = m & 1, b = m >> 5;
  int pk = selrk[m];
  int e = pk & 7, r = pk >> 3;
  int gslot = blockhist[b * NEXP + e] + r;
  elist[e * NTOK + gslot] = t;
  ((int*)meta)[t * 4 + 2 + c] = gslot;
}

// ---------------- GEMM1: h = gelu(X_gathered @ W1[e]) ----------------
__global__ __launch_bounds__(256) void gemm1_kernel(const u16* __restrict__ xb,
                                                    const u16* __restrict__ w1t,
                                                    u16* __restrict__ h,
                                                    const int* __restrict__ elist,
                                                    const int* __restrict__ cnt,
                                                    const int* __restrict__ offs){
  const int e = blockIdx.z;
  const int n_e = cnt[e];
  const int tt = blockIdx.y;
  if (tt * 128 >= n_e) return;
  const int hb = blockIdx.x * 128;
  __shared__ __align__(16) u16 As[128 * 64];
  __shared__ __align__(16) u16 Bs[128 * 64];
  const int tid = threadIdx.x;
  const int colb = (tid & 7) * 8;
  long agb[4]; int arow[4];
#pragma unroll
  for (int q = 0; q < 4; q++){
    int row = q * 32 + (tid >> 3);
    int slot = tt * 128 + row;
    int sl = slot < n_e ? slot : n_e - 1;
    int tok = elist[e * NTOK + sl];
    arow[q] = row;
    agb[q] = (long)tok * DDIM + colb;
  }
  const long bgb = ((long)e * HDIM + hb) * DDIM;
  const int wid = tid >> 6, lane = tid & 63;
  const int wr = (wid >> 1) * 64, wc = (wid & 1) * 64;
  const int fr = lane & 15, fq = lane >> 4;
  f32x4 acc[4][4] = {};
  for (int kb = 0; kb < DDIM; kb += 64){
    __syncthreads();
#pragma unroll
    for (int q = 0; q < 4; q++){
      int row = q * 32 + (tid >> 3);
      gl_lds16(xb + agb[q] + kb, &As[arow[q] * 64 + colb]);
      gl_lds16(w1t + bgb + (long)row * DDIM + kb + colb, &Bs[row * 64 + colb]);
    }
    __syncthreads();
#pragma unroll
    for (int kk = 0; kk < 2; kk++){
      bf16x8 af[4], bfr[4];
#pragma unroll
      for (int m = 0; m < 4; m++) af[m] = *(const bf16x8*)&As[(wr + m * 16 + fr) * 64 + kk * 32 + fq * 8];
#pragma unroll
      for (int n = 0; n < 4; n++) bfr[n] = *(const bf16x8*)&Bs[(wc + n * 16 + fr) * 64 + kk * 32 + fq * 8];
#pragma unroll
      for (int m = 0; m < 4; m++)
#pragma unroll
        for (int n = 0; n < 4; n++)
          acc[m][n] = __builtin_amdgcn_mfma_f32_16x16x32_bf16(af[m], bfr[n], acc[m][n], 0, 0, 0);
    }
  }
  const int hrow0 = offs[e] + tt * 128;
#pragma unroll
  for (int m = 0; m < 4; m++){
#pragma unroll
    for (int j = 0; j < 4; j++){
      int row = wr + m * 16 + fq * 4 + j;
      int slot = tt * 128 + row;
      if (slot >= n_e) continue;
      long base = (long)(hrow0 + row) * HDIM + hb + wc;
#pragma unroll
      for (int n = 0; n < 4; n++){
        float v = acc[m][n][j];
        v = 0.5f * v * (1.0f + erff(v * 0.70710678118f));   // exact gelu
        h[base + n * 16 + fr] = f2bf(v);
      }
    }
  }
}

// ---------------- GEMM2: ypair = h @ W2[e] ----------------
__global__ __launch_bounds__(256) void gemm2_kernel(const u16* __restrict__ h,
                                                    const u16* __restrict__ w2t,
                                                    u16* __restrict__ ypair,
                                                    const int* __restrict__ cnt,
                                                    const int* __restrict__ offs){
  const int e = blockIdx.z;
  const int n_e = cnt[e];
  const int tt = blockIdx.y;
  if (tt * 128 >= n_e) return;
  const int db = blockIdx.x * 128;
  __shared__ __align__(16) u16 As[128 * 64];
  __shared__ __align__(16) u16 Bs[128 * 64];
  const int tid = threadIdx.x;
  const int colb = (tid & 7) * 8;
  const long arow0 = (long)(offs[e] + tt * 128);
  const long bgb = ((long)e * DDIM + db) * HDIM;
  const int wid = tid >> 6, lane = tid & 63;
  const int wr = (wid >> 1) * 64, wc = (wid & 1) * 64;
  const int fr = lane & 15, fq = lane >> 4;
  f32x4 acc[4][4] = {};
  for (int kb = 0; kb < HDIM; kb += 64){
    __syncthreads();
#pragma unroll
    for (int q = 0; q < 4; q++){
      int row = q * 32 + (tid >> 3);
      gl_lds16(h + (arow0 + row) * HDIM + kb + colb, &As[row * 64 + colb]);
      gl_lds16(w2t + bgb + (long)row * HDIM + kb + colb, &Bs[row * 64 + colb]);
    }
    __syncthreads();
#pragma unroll
    for (int kk = 0; kk < 2; kk++){
      bf16x8 af[4], bfr[4];
#pragma unroll
      for (int m = 0; m < 4; m++) af[m] = *(const bf16x8*)&As[(wr + m * 16 + fr) * 64 + kk * 32 + fq * 8];
#pragma unroll
      for (int n = 0; n < 4; n++) bfr[n] = *(const bf16x8*)&Bs[(wc + n * 16 + fr) * 64 + kk * 32 + fq * 8];
#pragma unroll
      for (int m = 0; m < 4; m++)
#pragma unroll
        for (int n = 0; n < 4; n++)
          acc[m][n] = __builtin_amdgcn_mfma_f32_16x16x32_bf16(af[m], bfr[n], acc[m][n], 0, 0, 0);
    }
  }
  const long prow0 = arow0;
#pragma unroll
  for (int m = 0; m < 4; m++){
#pragma unroll
    for (int j = 0; j < 4; j++){
      int row = wr + m * 16 + fq * 4 + j;
      int slot = tt * 128 + row;
      if (slot >= n_e) continue;
      long base = (prow0 + row) * DDIM + db + wc;
#pragma unroll
      for (int n = 0; n < 4; n++) ypair[base + n * 16 + fr] = f2bf(acc[m][n][j]);
    }
  }
}

// ---------------- combine: out[t] = g0*y0 + g1*y1 ----------------
__global__ __launch_bounds__(256) void combine_kernel(const u16* __restrict__ ypair,
                                                      const int4* __restrict__ meta,
                                                      const float2* __restrict__ gates,
                                                      const int* __restrict__ offs,
                                                      float* __restrict__ out){
  int t = blockIdx.x;
  int c = threadIdx.x;
  int4 m = meta[t];
  float2 g = gates[t];
  long p0 = (long)(offs[m.x] + m.z) * DDIM + c * 4;
  long p1 = (long)(offs[m.y] + m.w) * DDIM + c * 4;
  u16x4 y0 = *(const u16x4*)&ypair[p0];
  u16x4 y1 = *(const u16x4*)&ypair[p1];
  float4 o;
  o.x = g.x * bf2f(y0[0]) + g.y * bf2f(y1[0]);
  o.y = g.x * bf2f(y0[1]) + g.y * bf2f(y1[1]);
  o.z = g.x * bf2f(y0[2]) + g.y * bf2f(y1[2]);
  o.w = g.x * bf2f(y0[3]) + g.y * bf2f(y1[3]);
  *(float4*)&out[(long)t * DDIM + c * 4] = o;
}

// ---------------- load-balance loss ----------------
__global__ void lb_kernel(const float* __restrict__ imp, const int* __restrict__ cnt,
                          float* __restrict__ outp){
  if (threadIdx.x == 0 && blockIdx.x == 0){
    float si = 0.f, sl = 0.f;
    for (int e = 0; e < NEXP; e++){ si += imp[e]; sl += (float)cnt[e]; }
    float lb = 0.f;
    for (int e = 0; e < NEXP; e++)
      lb += (imp[e] / (si + 1e-9f)) * ((float)cnt[e] / (sl + 1e-9f));
    outp[0] = lb * (float)NEXP;
  }
}

extern "C" void kernel_launch(void* const* d_in, const int* in_sizes, int n_in,
                              void* d_out, int out_size, void* d_ws, size_t ws_size,
                              hipStream_t stream){
  const float* x  = (const float*)d_in[0];
  const float* Wr = (const float*)d_in[1];
  const float* W1 = (const float*)d_in[2];
  const float* W2 = (const float*)d_in[3];
  float* out = (float*)d_out;
  char* ws = (char*)d_ws;
  size_t off = 0;
  u16* xb = (u16*)(ws + off);   off += (size_t)NTOK * DDIM * 2;
  u16* wt = (u16*)(ws + off);   off += (size_t)NEXP * DDIM * HDIM * 2;   // reused: W1^T then W2^T
  u16* h  = (u16*)(ws + off);   off += (size_t)HROWS * HDIM * 2;
  u16* yp = (u16*)(ws + off);   off += (size_t)NTOK * 2 * DDIM * 2;
  int* elist    = (int*)(ws + off);    off += (size_t)NEXP * NTOK * 4;
  int4* meta    = (int4*)(ws + off);   off += (size_t)NTOK * 16;
  float2* gts   = (float2*)(ws + off); off += (size_t)NTOK * 8;
  int* selrk    = (int*)(ws + off);    off += (size_t)NTOK * 2 * 4;
  int* bhist    = (int*)(ws + off);    off += (size_t)RBLK * NEXP * 4;
  float* impP   = (float*)(ws + off);  off += (size_t)RBLK * NEXP * 4;
  int* cnt      = (int*)(ws + off);    off += 32;
  float* imp    = (float*)(ws + off);  off += 32;
  int* offs     = (int*)(ws + off);    off += 32;
  if (ws_size < off) return;  // insufficient workspace: fail visibly

  cvtx_kernel<<<4096, 256, 0, stream>>>(x, xb);
  route_kernel<<<RBLK, 1024, 0, stream>>>(x, Wr, meta, gts, selrk, bhist, impP);
  scan_kernel<<<1, 512, 0, stream>>>(bhist, impP, cnt, offs, imp);
  fill_kernel<<<NTOK * 2 / 256, 256, 0, stream>>>(selrk, bhist, elist, meta);
  transpose_cvt<<<dim3(HDIM / 64, DDIM / 64, NEXP), 256, 0, stream>>>(W1, wt, DDIM, HDIM);
  gemm1_kernel<<<dim3(HDIM / 128, NTOK / 128, NEXP), 256, 0, stream>>>(xb, wt, h, elist, cnt, offs);
  transpose_cvt<<<dim3(DDIM / 64, HDIM / 64, NEXP), 256, 0, stream>>>(W2, wt, HDIM, DDIM);
  gemm2_kernel<<<dim3(DDIM / 128, NTOK / 128, NEXP), 256, 0, stream>>>(h, wt, yp, cnt, offs);
  combine_kernel<<<NTOK, 256, 0, stream>>>(yp, meta, gts, offs, out);
  lb_kernel<<<1, 64, 0, stream>>>(imp, cnt, out + (size_t)NTOK * DDIM);
}